// Round 1
// 686.793 us; speedup vs baseline: 1.1127x; 1.1127x over previous
//
#include <hip/hip_runtime.h>
#include <hip/hip_bf16.h>
#include <math.h>

// Problem constants (B=2, L=1024 -> T=2048 tokens)
#define T_TOK 2048
#define Dd    2048
#define Ee    8
#define Hh    1408
#define HSs   2816
#define CAP   1024   // per-expert token capacity (mean 512, sigma ~21)

typedef __attribute__((ext_vector_type(8))) __bf16 bf16x8;
typedef __attribute__((ext_vector_type(4))) __bf16 bf16x4;
typedef __attribute__((ext_vector_type(4))) float  f32x4;

#define MFMA(a, b, c) __builtin_amdgcn_mfma_f32_16x16x32_bf16(a, b, c, 0, 0, 0)

// async global->LDS 16B/lane copy (lane-contiguous LDS dest required)
__device__ __forceinline__ void async_copy16(const __bf16* g, __bf16* l) {
    __builtin_amdgcn_global_load_lds(
        (const __attribute__((address_space(1))) unsigned int*)g,
        (__attribute__((address_space(3))) unsigned int*)l, 16, 0, 0);
}

// ---------------------------------------------------------------------------
// init: zero per-expert counters
// ---------------------------------------------------------------------------
__global__ void init_cnt(int* __restrict__ cnt) {
    if (threadIdx.x < Ee) cnt[threadIdx.x] = 0;
}

// ---------------------------------------------------------------------------
// router (fp32): logits, top-2 renorm weights, packed per-expert lists,
// per-token (slot, weight) for the combine pass, shared sigmoid gate.
// Also emits xb (bf16 cast of x) since we're already streaming x.
// ---------------------------------------------------------------------------
__global__ __launch_bounds__(256) void router_kernel(
    const float* __restrict__ x, const float* __restrict__ gate_w,
    const float* __restrict__ shgate_w,
    int* __restrict__ cnt, int* __restrict__ ptok,
    int* __restrict__ slot, float* __restrict__ swt,
    float* __restrict__ sgate, __bf16* __restrict__ xb)
{
    const int t = blockIdx.x;
    const int tid = threadIdx.x;
    const float* xt = x + (size_t)t * Dd;

    float acc[Ee];
#pragma unroll
    for (int e = 0; e < Ee; e++) acc[e] = 0.f;
    float accs = 0.f;

    for (int d = tid; d < Dd; d += 256) {
        float xv = xt[d];
        xb[(size_t)t * Dd + d] = (__bf16)xv;
#pragma unroll
        for (int e = 0; e < Ee; e++) acc[e] += xv * gate_w[e * Dd + d];
        accs += xv * shgate_w[d];
    }

    __shared__ float red[Ee + 1][256];
#pragma unroll
    for (int e = 0; e < Ee; e++) red[e][tid] = acc[e];
    red[Ee][tid] = accs;
    __syncthreads();

    for (int s = 128; s > 0; s >>= 1) {
        if (tid < s) {
#pragma unroll
            for (int e = 0; e <= Ee; e++) red[e][tid] += red[e][tid + s];
        }
        __syncthreads();
    }

    if (tid == 0) {
        float l0 = -1e30f, l1 = -1e30f;
        int i0 = 0, i1 = 0;
#pragma unroll
        for (int e = 0; e < Ee; e++) {
            float v = red[e][0];
            if (v > l0) { l1 = l0; i1 = i0; l0 = v; i0 = e; }
            else if (v > l1) { l1 = v; i1 = e; }
        }
        float w0 = 1.f / (1.f + expf(l1 - l0));  // renormalized top-2
        float w1 = 1.f - w0;

        int p0 = atomicAdd(&cnt[i0], 1);
        if (p0 < CAP) { ptok[i0 * CAP + p0] = t; slot[t * 2] = i0 * CAP + p0; swt[t * 2] = w0; }
        else          { slot[t * 2] = 0; swt[t * 2] = 0.f; }
        int p1 = atomicAdd(&cnt[i1], 1);
        if (p1 < CAP) { ptok[i1 * CAP + p1] = t; slot[t * 2 + 1] = i1 * CAP + p1; swt[t * 2 + 1] = w1; }
        else          { slot[t * 2 + 1] = 0; swt[t * 2 + 1] = 0.f; }

        sgate[t] = 1.f / (1.f + expf(-red[Ee][0]));
    }
}

// ---------------------------------------------------------------------------
// transpose_cvt: src fp32 [R][C] (batched) -> dst bf16 [C][R]
// grid (C/32, R/32, batch), block (32, 8)
// ---------------------------------------------------------------------------
__global__ __launch_bounds__(256) void transpose_cvt(
    const float* __restrict__ src, __bf16* __restrict__ dst, int R, int C)
{
    const size_t bstride = (size_t)R * C;
    src += blockIdx.z * bstride;
    dst += blockIdx.z * bstride;
    __shared__ float tile[32][33];
    const int tx = threadIdx.x, ty = threadIdx.y;
    const int c0 = blockIdx.x * 32, r0 = blockIdx.y * 32;
#pragma unroll
    for (int j = 0; j < 4; j++)
        tile[ty + 8 * j][tx] = src[(size_t)(r0 + ty + 8 * j) * C + c0 + tx];
    __syncthreads();
#pragma unroll
    for (int j = 0; j < 4; j++)
        dst[(size_t)(c0 + ty + 8 * j) * R + r0 + tx] = (__bf16)tile[tx][ty + 8 * j];
}

// ---------------------------------------------------------------------------
// gateup_all: merged expert + shared gate/up GEMM, 2-phase prefetch dbuf.
// Block = 128 rows x 64 h (gate AND up => effective 128x128 output).
// Shared part first (704 blocks), then expert part (1408 blocks, ~half live).
// K = D = 2048 for both paths.
// ---------------------------------------------------------------------------
#define GU_SH_BLOCKS ((T_TOK / 128) * (HSs / 64))   // 16*44 = 704
#define GU_EX_BLOCKS (Ee * 8 * (Hh / 64))           // 64*22 = 1408

__global__ __launch_bounds__(256, 3) void gateup_all(
    const __bf16* __restrict__ xb,
    const __bf16* __restrict__ wgT, const __bf16* __restrict__ wuT,   // [E][H][D]
    const __bf16* __restrict__ swgT, const __bf16* __restrict__ swuT, // [HS][D]
    const int* __restrict__ cnt, const int* __restrict__ ptok,
    __bf16* __restrict__ hq, __bf16* __restrict__ shh)
{
    const int tid = threadIdx.x, lane = tid & 63, wave = tid >> 6;
    __shared__ __align__(16) __bf16 As[2][128 * 32];
    __shared__ __align__(16) __bf16 Bg[2][64 * 32];
    __shared__ __align__(16) __bf16 Bu[2][64 * 32];
    __shared__ int tok_s[128];

    const int bid = blockIdx.x;
    const int kq = (tid & 3) * 8;
    const __bf16 *wg, *wu, *ga1, *ga2;
    __bf16* outp;
    int ostride, m0, h0;

    if (bid < GU_SH_BLOCKS) {
        // shared expert: dense rows
        int ht = bid % 44, mt = bid / 44;   // ht in low bits: weight-panel XCD locality
        m0 = mt * 128; h0 = ht * 64;
        wg = swgT; wu = swuT;
        outp = shh; ostride = HSs;
        ga1 = xb + (size_t)(m0 + (tid >> 2)) * Dd + kq;
        ga2 = xb + (size_t)(m0 + 64 + (tid >> 2)) * Dd + kq;
    } else {
        int b2 = bid - GU_SH_BLOCKS;
        int em = b2 & 63, ht = b2 >> 6;
        int e = em & 7, mt = em >> 3;       // e in low 3 bits -> expert pinned to XCD
        int n = cnt[e]; if (n > CAP) n = CAP;
        m0 = mt * 128;
        if (m0 >= n) return;
        h0 = ht * 64;
        wg = wgT + (size_t)e * Hh * Dd; wu = wuT + (size_t)e * Hh * Dd;
        outp = hq + (size_t)e * CAP * Hh; ostride = Hh;
        if (tid < 128) {
            int i = m0 + tid; int ic = i < n ? i : n - 1;
            tok_s[tid] = ptok[e * CAP + ic];
        }
        __syncthreads();
        ga1 = xb + (size_t)tok_s[tid >> 2] * Dd + kq;
        ga2 = xb + (size_t)tok_s[64 + (tid >> 2)] * Dd + kq;
    }
    const __bf16* gbg = wg + (size_t)(h0 + (tid >> 2)) * Dd + kq;
    const __bf16* gbu = wu + (size_t)(h0 + (tid >> 2)) * Dd + kq;

    f32x4 accg[2][4] = {}, accu[2][4] = {};
    const int q = lane >> 4, m = lane & 15;

#define GU_STAGE(bb, k0) do {                              \
    async_copy16(ga1 + (k0), As[bb] + tid * 8);            \
    async_copy16(ga2 + (k0), As[bb] + (tid + 256) * 8);    \
    async_copy16(gbg + (k0), Bg[bb] + tid * 8);            \
    async_copy16(gbu + (k0), Bu[bb] + tid * 8); } while (0)

    GU_STAGE(0, 0);
    __syncthreads();                 // drains vmcnt(0): buf0 ready
    int cur = 0;
    for (int t = 0; t < Dd / 32; ++t) {
        if (t + 1 < Dd / 32) GU_STAGE(cur ^ 1, (t + 1) * 32);  // prefetch flies under MFMA
        bf16x8 af[2], bgf[4], buf_[4];
        af[0] = *(const bf16x8*)(As[cur] + (wave * 32 + m) * 32 + q * 8);
        af[1] = *(const bf16x8*)(As[cur] + (wave * 32 + 16 + m) * 32 + q * 8);
#pragma unroll
        for (int j = 0; j < 4; j++) {
            bgf[j]  = *(const bf16x8*)(Bg[cur] + (j * 16 + m) * 32 + q * 8);
            buf_[j] = *(const bf16x8*)(Bu[cur] + (j * 16 + m) * 32 + q * 8);
        }
#pragma unroll
        for (int i = 0; i < 2; i++)
#pragma unroll
            for (int j = 0; j < 4; j++) {
                accg[i][j] = MFMA(af[i], bgf[j], accg[i][j]);
                accu[i][j] = MFMA(af[i], buf_[j], accu[i][j]);
            }
        __syncthreads();             // one barrier per K-step (drains prefetch too)
        cur ^= 1;
    }
#undef GU_STAGE

#pragma unroll
    for (int i = 0; i < 2; i++)
#pragma unroll
        for (int r = 0; r < 4; r++) {
            int row = m0 + wave * 32 + i * 16 + q * 4 + r;
#pragma unroll
            for (int j = 0; j < 4; j++) {
                int h = h0 + j * 16 + m;
                float g = accg[i][j][r], u = accu[i][j][r];
                float s = g / (1.f + __expf(-g));
                outp[(size_t)row * ostride + h] = (__bf16)(s * u);
            }
        }
}

// ---------------------------------------------------------------------------
// down_all: merged shared + expert down-proj, 128x128 tiles, prefetch dbuf.
// Shared: out[t][d] = sgate[t] * (shh @ shwdT)   (plain store, full coverage)
// Expert: dexp[e*CAP+row][d] = hq_row @ wdT[e]   (packed rows, NO atomics;
//         routing weight applied later in combine_kernel)
// K is runtime: HSs (shared) or Hh (expert).
// ---------------------------------------------------------------------------
#define DN_SH_BLOCKS ((T_TOK / 128) * (Dd / 128))   // 16*16 = 256
#define DN_EX_BLOCKS (Ee * 8 * (Dd / 128))          // 64*16 = 1024

__global__ __launch_bounds__(256, 3) void down_all(
    const __bf16* __restrict__ shh, const __bf16* __restrict__ shwdT,
    const __bf16* __restrict__ hq, const __bf16* __restrict__ wdT,
    const int* __restrict__ cnt, const float* __restrict__ sgate,
    float* __restrict__ out, float* __restrict__ dexp)
{
    const int tid = threadIdx.x, lane = tid & 63, wave = tid >> 6;
    const int wr = wave >> 1, wc = wave & 1;
    __shared__ __align__(16) __bf16 As[2][128 * 32];
    __shared__ __align__(16) __bf16 Bs[2][128 * 32];

    const int bid = blockIdx.x;
    const __bf16 *A, *BT;
    int m0, n0, K, shared_path, arow_base = 0;

    if (bid < DN_SH_BLOCKS) {
        int nt = bid & 15, mt = bid >> 4;   // nt in low bits: B-panel XCD locality
        m0 = mt * 128; n0 = nt * 128; K = HSs;
        A = shh; BT = shwdT; shared_path = 1;
    } else {
        int b2 = bid - DN_SH_BLOCKS;
        int em = b2 & 63, nt = b2 >> 6;
        int e = em & 7, mt = em >> 3;
        int n = cnt[e]; if (n > CAP) n = CAP;
        m0 = mt * 128;
        if (m0 >= n) return;
        n0 = nt * 128; K = Hh;
        A = hq + (size_t)e * CAP * Hh;       // packed rows: contiguous, no gather
        BT = wdT + (size_t)e * Dd * Hh;
        arow_base = e * CAP;
        shared_path = 0;
    }

    const int kq = (tid & 3) * 8;
    const __bf16* ga1 = A + (size_t)(m0 + (tid >> 2)) * K + kq;
    const __bf16* ga2 = A + (size_t)(m0 + 64 + (tid >> 2)) * K + kq;
    const __bf16* gb1 = BT + (size_t)(n0 + (tid >> 2)) * K + kq;
    const __bf16* gb2 = BT + (size_t)(n0 + 64 + (tid >> 2)) * K + kq;

    f32x4 acc[4][4] = {};
    const int q = lane >> 4, m = lane & 15;

#define DN_STAGE(bb, k0) do {                              \
    async_copy16(ga1 + (k0), As[bb] + tid * 8);            \
    async_copy16(ga2 + (k0), As[bb] + (tid + 256) * 8);    \
    async_copy16(gb1 + (k0), Bs[bb] + tid * 8);            \
    async_copy16(gb2 + (k0), Bs[bb] + (tid + 256) * 8); } while (0)

    DN_STAGE(0, 0);
    __syncthreads();
    int cur = 0;
    const int ntk = K / 32;
    for (int t = 0; t < ntk; ++t) {
        if (t + 1 < ntk) DN_STAGE(cur ^ 1, (t + 1) * 32);
        bf16x8 af[4], bf[4];
#pragma unroll
        for (int i = 0; i < 4; i++) {
            af[i] = *(const bf16x8*)(As[cur] + (wr * 64 + i * 16 + m) * 32 + q * 8);
            bf[i] = *(const bf16x8*)(Bs[cur] + (wc * 64 + i * 16 + m) * 32 + q * 8);
        }
#pragma unroll
        for (int i = 0; i < 4; i++)
#pragma unroll
            for (int j = 0; j < 4; j++)
                acc[i][j] = MFMA(af[i], bf[j], acc[i][j]);
        __syncthreads();
        cur ^= 1;
    }
#undef DN_STAGE

    if (shared_path) {
#pragma unroll
        for (int i = 0; i < 4; i++)
#pragma unroll
            for (int r = 0; r < 4; r++) {
                int trow = m0 + wr * 64 + i * 16 + q * 4 + r;
                float sg = sgate[trow];
#pragma unroll
                for (int j = 0; j < 4; j++)
                    out[(size_t)trow * Dd + n0 + wc * 64 + j * 16 + m] = sg * acc[i][j][r];
            }
    } else {
#pragma unroll
        for (int i = 0; i < 4; i++)
#pragma unroll
            for (int r = 0; r < 4; r++) {
                int row = arow_base + m0 + wr * 64 + i * 16 + q * 4 + r;
#pragma unroll
                for (int j = 0; j < 4; j++)
                    dexp[(size_t)row * Dd + n0 + wc * 64 + j * 16 + m] = acc[i][j][r];
            }
    }
}

// ---------------------------------------------------------------------------
// combine: out[t] += w0*dexp[slot0] + w1*dexp[slot1]  (one block per token,
// exactly one writer per element -> no atomics)
// ---------------------------------------------------------------------------
__global__ __launch_bounds__(256) void combine_kernel(
    const float* __restrict__ dexp, const int* __restrict__ slot,
    const float* __restrict__ swt, float* __restrict__ out)
{
    const int t = blockIdx.x, tid = threadIdx.x;
    const int s0 = slot[t * 2], s1 = slot[t * 2 + 1];
    const float w0 = swt[t * 2], w1 = swt[t * 2 + 1];
    const float4* d0 = (const float4*)(dexp + (size_t)s0 * Dd);
    const float4* d1 = (const float4*)(dexp + (size_t)s1 * Dd);
    float4* o = (float4*)(out + (size_t)t * Dd);
#pragma unroll
    for (int it = 0; it < 2; ++it) {
        int i = tid + it * 256;
        float4 a = o[i], b0 = d0[i], b1 = d1[i];
        a.x += w0 * b0.x + w1 * b1.x;
        a.y += w0 * b0.y + w1 * b1.y;
        a.z += w0 * b0.z + w1 * b1.z;
        a.w += w0 * b0.w + w1 * b1.w;
        o[i] = a;
    }
}

// ---------------------------------------------------------------------------
// launch
// ---------------------------------------------------------------------------
extern "C" void kernel_launch(void* const* d_in, const int* in_sizes, int n_in,
                              void* d_out, int out_size, void* d_ws, size_t ws_size,
                              hipStream_t stream) {
    const float* x        = (const float*)d_in[0];
    const float* gate_w   = (const float*)d_in[1];
    const float* w_gate   = (const float*)d_in[2];
    const float* w_up     = (const float*)d_in[3];
    const float* w_down   = (const float*)d_in[4];
    const float* shgate_w = (const float*)d_in[5];
    const float* shw_gate = (const float*)d_in[6];
    const float* shw_up   = (const float*)d_in[7];
    const float* shw_down = (const float*)d_in[8];
    float* out = (float*)d_out;

    // ---- workspace layout (bytes, 256-aligned) ----
    char* ws = (char*)d_ws;
    size_t off = 0;
    auto alloc = [&](size_t bytes) { char* p = ws + off; off = (off + bytes + 255) & ~(size_t)255; return p; };
    int*    cnt    = (int*)   alloc(Ee * 4);
    int*    ptok   = (int*)   alloc(Ee * CAP * 4);
    int*    slot   = (int*)   alloc(T_TOK * 2 * 4);
    float*  swt    = (float*) alloc(T_TOK * 2 * 4);
    float*  sgate  = (float*) alloc(T_TOK * 4);
    __bf16* xb     = (__bf16*)alloc((size_t)T_TOK * Dd * 2);
    __bf16* wgT    = (__bf16*)alloc((size_t)Ee * Hh * Dd * 2);
    __bf16* wuT    = (__bf16*)alloc((size_t)Ee * Hh * Dd * 2);
    __bf16* wdT    = (__bf16*)alloc((size_t)Ee * Dd * Hh * 2);
    __bf16* shwgT  = (__bf16*)alloc((size_t)HSs * Dd * 2);
    __bf16* shwuT  = (__bf16*)alloc((size_t)HSs * Dd * 2);
    __bf16* shwdT  = (__bf16*)alloc((size_t)Dd * HSs * 2);
    __bf16* hq     = (__bf16*)alloc((size_t)Ee * CAP * Hh * 2);
    __bf16* shh    = (__bf16*)alloc((size_t)T_TOK * HSs * 2);
    // dexp (E*CAP x D fp32 = 67 MB) aliases wgT+wuT (92 MB contiguous):
    // wgT/wuT are dead after gateup_all; down_all writes dexp, combine reads it,
    // and next iteration's transposes rewrite wgT before it is read again.
    float* dexp = (float*)wgT;

    dim3 b256(256), bT(32, 8);

    init_cnt<<<dim3(1), dim3(64), 0, stream>>>(cnt);
    // weight transposes: src [R][C] fp32 -> dst [C][R] bf16
    transpose_cvt<<<dim3(Hh / 32, Dd / 32, Ee), bT, 0, stream>>>(w_gate, wgT, Dd, Hh);
    transpose_cvt<<<dim3(Hh / 32, Dd / 32, Ee), bT, 0, stream>>>(w_up, wuT, Dd, Hh);
    transpose_cvt<<<dim3(Dd / 32, Hh / 32, Ee), bT, 0, stream>>>(w_down, wdT, Hh, Dd);
    transpose_cvt<<<dim3(HSs / 32, Dd / 32, 1), bT, 0, stream>>>(shw_gate, shwgT, Dd, HSs);
    transpose_cvt<<<dim3(HSs / 32, Dd / 32, 1), bT, 0, stream>>>(shw_up, shwuT, Dd, HSs);
    transpose_cvt<<<dim3(Dd / 32, HSs / 32, 1), bT, 0, stream>>>(shw_down, shwdT, HSs, Dd);

    router_kernel<<<dim3(T_TOK), b256, 0, stream>>>(x, gate_w, shgate_w,
                                                    cnt, ptok, slot, swt, sgate, xb);

    gateup_all<<<dim3(GU_SH_BLOCKS + GU_EX_BLOCKS), b256, 0, stream>>>(
        xb, wgT, wuT, shwgT, shwuT, cnt, ptok, hq, shh);

    down_all<<<dim3(DN_SH_BLOCKS + DN_EX_BLOCKS), b256, 0, stream>>>(
        shh, shwdT, hq, wdT, cnt, sgate, out, dexp);

    combine_kernel<<<dim3(T_TOK), b256, 0, stream>>>(dexp, slot, swt, out);
}

// Round 2
// 685.699 us; speedup vs baseline: 1.1145x; 1.0016x over previous
//
#include <hip/hip_runtime.h>
#include <hip/hip_bf16.h>
#include <math.h>

// Problem constants (B=2, L=1024 -> T=2048 tokens)
#define T_TOK 2048
#define Dd    2048
#define Ee    8
#define Hh    1408
#define HSs   2816
#define CAP   1024   // per-expert token capacity (mean 512, sigma ~21)

typedef __attribute__((ext_vector_type(8))) __bf16 bf16x8;
typedef __attribute__((ext_vector_type(4))) __bf16 bf16x4;
typedef __attribute__((ext_vector_type(4))) float  f32x4;

#define MFMA(a, b, c) __builtin_amdgcn_mfma_f32_16x16x32_bf16(a, b, c, 0, 0, 0)

// async global->LDS 16B/lane copy (lane-contiguous LDS dest required)
__device__ __forceinline__ void async_copy16(const __bf16* g, __bf16* l) {
    __builtin_amdgcn_global_load_lds(
        (const __attribute__((address_space(1))) unsigned int*)g,
        (__attribute__((address_space(3))) unsigned int*)l, 16, 0, 0);
}

// ---------------------------------------------------------------------------
// LDS anti-bank-conflict swizzle (T2, both-sides-or-neither per rule #21):
// tiles are [rows][32] bf16 = [rows][4 colblocks of 16B]. Linear row stride
// 64B makes 16-lane fragment reads 8-way bank-conflicted. We permute
// colblocks: physical cb = logical cb ^ ((row>>1)&3).
//  - staging: LDS dest stays lane-linear (tid*16B); the global SOURCE lane
//    offset is pre-swizzled: kq = ((tid&3) ^ ((tid>>3)&3)) * 8 elems.
//    (row = tid>>2 -> (row>>1)&3 = (tid>>3)&3; holds for +64-row halves too.)
//  - reads: every fragment row is (mult-of-8) + m, so the read colblock is
//    q ^ ((m>>1)&3). 16 lanes then cover all 8 bank-groups, 2 lanes each
//    (2-way = free, m136).
// ---------------------------------------------------------------------------

// ---------------------------------------------------------------------------
// init: zero per-expert counters
// ---------------------------------------------------------------------------
__global__ void init_cnt(int* __restrict__ cnt) {
    if (threadIdx.x < Ee) cnt[threadIdx.x] = 0;
}

// ---------------------------------------------------------------------------
// router (fp32): logits, top-2 renorm weights, packed per-expert lists,
// per-token (slot, weight) for the combine pass, shared sigmoid gate.
// Also emits xb (bf16 cast of x) since we're already streaming x.
// ---------------------------------------------------------------------------
__global__ __launch_bounds__(256) void router_kernel(
    const float* __restrict__ x, const float* __restrict__ gate_w,
    const float* __restrict__ shgate_w,
    int* __restrict__ cnt, int* __restrict__ ptok,
    int* __restrict__ slot, float* __restrict__ swt,
    float* __restrict__ sgate, __bf16* __restrict__ xb)
{
    const int t = blockIdx.x;
    const int tid = threadIdx.x;
    const float* xt = x + (size_t)t * Dd;

    float acc[Ee];
#pragma unroll
    for (int e = 0; e < Ee; e++) acc[e] = 0.f;
    float accs = 0.f;

    for (int d = tid; d < Dd; d += 256) {
        float xv = xt[d];
        xb[(size_t)t * Dd + d] = (__bf16)xv;
#pragma unroll
        for (int e = 0; e < Ee; e++) acc[e] += xv * gate_w[e * Dd + d];
        accs += xv * shgate_w[d];
    }

    __shared__ float red[Ee + 1][256];
#pragma unroll
    for (int e = 0; e < Ee; e++) red[e][tid] = acc[e];
    red[Ee][tid] = accs;
    __syncthreads();

    for (int s = 128; s > 0; s >>= 1) {
        if (tid < s) {
#pragma unroll
            for (int e = 0; e <= Ee; e++) red[e][tid] += red[e][tid + s];
        }
        __syncthreads();
    }

    if (tid == 0) {
        float l0 = -1e30f, l1 = -1e30f;
        int i0 = 0, i1 = 0;
#pragma unroll
        for (int e = 0; e < Ee; e++) {
            float v = red[e][0];
            if (v > l0) { l1 = l0; i1 = i0; l0 = v; i0 = e; }
            else if (v > l1) { l1 = v; i1 = e; }
        }
        float w0 = 1.f / (1.f + expf(l1 - l0));  // renormalized top-2
        float w1 = 1.f - w0;

        int p0 = atomicAdd(&cnt[i0], 1);
        if (p0 < CAP) { ptok[i0 * CAP + p0] = t; slot[t * 2] = i0 * CAP + p0; swt[t * 2] = w0; }
        else          { slot[t * 2] = 0; swt[t * 2] = 0.f; }
        int p1 = atomicAdd(&cnt[i1], 1);
        if (p1 < CAP) { ptok[i1 * CAP + p1] = t; slot[t * 2 + 1] = i1 * CAP + p1; swt[t * 2 + 1] = w1; }
        else          { slot[t * 2 + 1] = 0; swt[t * 2 + 1] = 0.f; }

        sgate[t] = 1.f / (1.f + expf(-red[Ee][0]));
    }
}

// ---------------------------------------------------------------------------
// transpose_cvt: src fp32 [R][C] (batched) -> dst bf16 [C][R]
// grid (C/32, R/32, batch), block (32, 8). Write phase uses 8B bf16x4
// stores (vs old 2B scalar).
// ---------------------------------------------------------------------------
__global__ __launch_bounds__(256) void transpose_cvt(
    const float* __restrict__ src, __bf16* __restrict__ dst, int R, int C)
{
    const size_t bstride = (size_t)R * C;
    src += blockIdx.z * bstride;
    dst += blockIdx.z * bstride;
    __shared__ float tile[32][33];
    const int tx = threadIdx.x, ty = threadIdx.y;
    const int c0 = blockIdx.x * 32, r0 = blockIdx.y * 32;
#pragma unroll
    for (int j = 0; j < 4; j++)
        tile[ty + 8 * j][tx] = src[(size_t)(r0 + ty + 8 * j) * C + c0 + tx];
    __syncthreads();
    const int tid = ty * 32 + tx;
    const int cc = tid >> 3, r4 = (tid & 7) * 4;
    bf16x4 o = { (__bf16)tile[r4 + 0][cc], (__bf16)tile[r4 + 1][cc],
                 (__bf16)tile[r4 + 2][cc], (__bf16)tile[r4 + 3][cc] };
    *(bf16x4*)(dst + (size_t)(c0 + cc) * R + r0 + r4) = o;
}

// ---------------------------------------------------------------------------
// gateup_all: merged expert + shared gate/up GEMM, 2-phase prefetch dbuf,
// swizzled LDS. Block = 128 rows x 64 h (gate AND up).
// ---------------------------------------------------------------------------
#define GU_SH_BLOCKS ((T_TOK / 128) * (HSs / 64))   // 16*44 = 704
#define GU_EX_BLOCKS (Ee * 8 * (Hh / 64))           // 64*22 = 1408

__global__ __launch_bounds__(256, 3) void gateup_all(
    const __bf16* __restrict__ xb,
    const __bf16* __restrict__ wgT, const __bf16* __restrict__ wuT,   // [E][H][D]
    const __bf16* __restrict__ swgT, const __bf16* __restrict__ swuT, // [HS][D]
    const int* __restrict__ cnt, const int* __restrict__ ptok,
    __bf16* __restrict__ hq, __bf16* __restrict__ shh)
{
    const int tid = threadIdx.x, lane = tid & 63, wave = tid >> 6;
    __shared__ __align__(16) __bf16 As[2][128 * 32];
    __shared__ __align__(16) __bf16 Bg[2][64 * 32];
    __shared__ __align__(16) __bf16 Bu[2][64 * 32];
    __shared__ int tok_s[128];

    const int bid = blockIdx.x;
    // swizzled source k-offset for staging (see swizzle comment above)
    const int kq = (((tid & 3) ^ ((tid >> 3) & 3)) * 8);
    const __bf16 *wg, *wu, *ga1, *ga2;
    __bf16* outp;
    int ostride, m0, h0;

    if (bid < GU_SH_BLOCKS) {
        // shared expert: dense rows
        int ht = bid % 44, mt = bid / 44;   // ht in low bits: weight-panel XCD locality
        m0 = mt * 128; h0 = ht * 64;
        wg = swgT; wu = swuT;
        outp = shh; ostride = HSs;
        ga1 = xb + (size_t)(m0 + (tid >> 2)) * Dd + kq;
        ga2 = xb + (size_t)(m0 + 64 + (tid >> 2)) * Dd + kq;
    } else {
        int b2 = bid - GU_SH_BLOCKS;
        int em = b2 & 63, ht = b2 >> 6;
        int e = em & 7, mt = em >> 3;       // e in low 3 bits -> expert pinned to XCD
        int n = cnt[e]; if (n > CAP) n = CAP;
        m0 = mt * 128;
        if (m0 >= n) return;
        h0 = ht * 64;
        wg = wgT + (size_t)e * Hh * Dd; wu = wuT + (size_t)e * Hh * Dd;
        outp = hq + (size_t)e * CAP * Hh; ostride = Hh;
        if (tid < 128) {
            int i = m0 + tid; int ic = i < n ? i : n - 1;
            tok_s[tid] = ptok[e * CAP + ic];
        }
        __syncthreads();
        ga1 = xb + (size_t)tok_s[tid >> 2] * Dd + kq;
        ga2 = xb + (size_t)tok_s[64 + (tid >> 2)] * Dd + kq;
    }
    const __bf16* gbg = wg + (size_t)(h0 + (tid >> 2)) * Dd + kq;
    const __bf16* gbu = wu + (size_t)(h0 + (tid >> 2)) * Dd + kq;

    f32x4 accg[2][4] = {}, accu[2][4] = {};
    const int q = lane >> 4, m = lane & 15;
    // swizzled read colblock: q ^ ((m>>1)&3), in elements
    const int cbr = (q ^ ((m >> 1) & 3)) * 8;

#define GU_STAGE(bb, k0) do {                              \
    async_copy16(ga1 + (k0), As[bb] + tid * 8);            \
    async_copy16(ga2 + (k0), As[bb] + (tid + 256) * 8);    \
    async_copy16(gbg + (k0), Bg[bb] + tid * 8);            \
    async_copy16(gbu + (k0), Bu[bb] + tid * 8); } while (0)

    GU_STAGE(0, 0);
    __syncthreads();                 // drains vmcnt(0): buf0 ready
    int cur = 0;
    for (int t = 0; t < Dd / 32; ++t) {
        if (t + 1 < Dd / 32) GU_STAGE(cur ^ 1, (t + 1) * 32);  // prefetch flies under MFMA
        bf16x8 af[2], bgf[4], buf_[4];
        af[0] = *(const bf16x8*)(As[cur] + (wave * 32 + m) * 32 + cbr);
        af[1] = *(const bf16x8*)(As[cur] + (wave * 32 + 16 + m) * 32 + cbr);
#pragma unroll
        for (int j = 0; j < 4; j++) {
            bgf[j]  = *(const bf16x8*)(Bg[cur] + (j * 16 + m) * 32 + cbr);
            buf_[j] = *(const bf16x8*)(Bu[cur] + (j * 16 + m) * 32 + cbr);
        }
#pragma unroll
        for (int i = 0; i < 2; i++)
#pragma unroll
            for (int j = 0; j < 4; j++) {
                accg[i][j] = MFMA(af[i], bgf[j], accg[i][j]);
                accu[i][j] = MFMA(af[i], buf_[j], accu[i][j]);
            }
        __syncthreads();             // one barrier per K-step (drains prefetch too)
        cur ^= 1;
    }
#undef GU_STAGE

#pragma unroll
    for (int i = 0; i < 2; i++)
#pragma unroll
        for (int r = 0; r < 4; r++) {
            int row = m0 + wave * 32 + i * 16 + q * 4 + r;
#pragma unroll
            for (int j = 0; j < 4; j++) {
                int h = h0 + j * 16 + m;
                float g = accg[i][j][r], u = accu[i][j][r];
                float s = g / (1.f + __expf(-g));
                outp[(size_t)row * ostride + h] = (__bf16)(s * u);
            }
        }
}

// ---------------------------------------------------------------------------
// down_all: merged shared + expert down-proj, 128x128 tiles, prefetch dbuf,
// swizzled LDS.
// Shared: out[t][d] = sgate[t] * (shh @ shwdT)   (plain store, full coverage)
// Expert: dexp[e*CAP+row][d] = hq_row @ wdT[e]   (packed rows, NO atomics)
// ---------------------------------------------------------------------------
#define DN_SH_BLOCKS ((T_TOK / 128) * (Dd / 128))   // 16*16 = 256
#define DN_EX_BLOCKS (Ee * 8 * (Dd / 128))          // 64*16 = 1024

__global__ __launch_bounds__(256, 3) void down_all(
    const __bf16* __restrict__ shh, const __bf16* __restrict__ shwdT,
    const __bf16* __restrict__ hq, const __bf16* __restrict__ wdT,
    const int* __restrict__ cnt, const float* __restrict__ sgate,
    float* __restrict__ out, float* __restrict__ dexp)
{
    const int tid = threadIdx.x, lane = tid & 63, wave = tid >> 6;
    const int wr = wave >> 1, wc = wave & 1;
    __shared__ __align__(16) __bf16 As[2][128 * 32];
    __shared__ __align__(16) __bf16 Bs[2][128 * 32];

    const int bid = blockIdx.x;
    const __bf16 *A, *BT;
    int m0, n0, K, shared_path, arow_base = 0;

    if (bid < DN_SH_BLOCKS) {
        int nt = bid & 15, mt = bid >> 4;   // nt in low bits: B-panel XCD locality
        m0 = mt * 128; n0 = nt * 128; K = HSs;
        A = shh; BT = shwdT; shared_path = 1;
    } else {
        int b2 = bid - DN_SH_BLOCKS;
        int em = b2 & 63, nt = b2 >> 6;
        int e = em & 7, mt = em >> 3;
        int n = cnt[e]; if (n > CAP) n = CAP;
        m0 = mt * 128;
        if (m0 >= n) return;
        n0 = nt * 128; K = Hh;
        A = hq + (size_t)e * CAP * Hh;       // packed rows: contiguous, no gather
        BT = wdT + (size_t)e * Dd * Hh;
        arow_base = e * CAP;
        shared_path = 0;
    }

    const int kq = (((tid & 3) ^ ((tid >> 3) & 3)) * 8);
    const __bf16* ga1 = A + (size_t)(m0 + (tid >> 2)) * K + kq;
    const __bf16* ga2 = A + (size_t)(m0 + 64 + (tid >> 2)) * K + kq;
    const __bf16* gb1 = BT + (size_t)(n0 + (tid >> 2)) * K + kq;
    const __bf16* gb2 = BT + (size_t)(n0 + 64 + (tid >> 2)) * K + kq;

    f32x4 acc[4][4] = {};
    const int q = lane >> 4, m = lane & 15;
    const int cbr = (q ^ ((m >> 1) & 3)) * 8;

#define DN_STAGE(bb, k0) do {                              \
    async_copy16(ga1 + (k0), As[bb] + tid * 8);            \
    async_copy16(ga2 + (k0), As[bb] + (tid + 256) * 8);    \
    async_copy16(gb1 + (k0), Bs[bb] + tid * 8);            \
    async_copy16(gb2 + (k0), Bs[bb] + (tid + 256) * 8); } while (0)

    DN_STAGE(0, 0);
    __syncthreads();
    int cur = 0;
    const int ntk = K / 32;
    for (int t = 0; t < ntk; ++t) {
        if (t + 1 < ntk) DN_STAGE(cur ^ 1, (t + 1) * 32);
        bf16x8 af[4], bf[4];
#pragma unroll
        for (int i = 0; i < 4; i++) {
            af[i] = *(const bf16x8*)(As[cur] + (wr * 64 + i * 16 + m) * 32 + cbr);
            bf[i] = *(const bf16x8*)(Bs[cur] + (wc * 64 + i * 16 + m) * 32 + cbr);
        }
#pragma unroll
        for (int i = 0; i < 4; i++)
#pragma unroll
            for (int j = 0; j < 4; j++)
                acc[i][j] = MFMA(af[i], bf[j], acc[i][j]);
        __syncthreads();
        cur ^= 1;
    }
#undef DN_STAGE

    if (shared_path) {
#pragma unroll
        for (int i = 0; i < 4; i++)
#pragma unroll
            for (int r = 0; r < 4; r++) {
                int trow = m0 + wr * 64 + i * 16 + q * 4 + r;
                float sg = sgate[trow];
#pragma unroll
                for (int j = 0; j < 4; j++)
                    out[(size_t)trow * Dd + n0 + wc * 64 + j * 16 + m] = sg * acc[i][j][r];
            }
    } else {
#pragma unroll
        for (int i = 0; i < 4; i++)
#pragma unroll
            for (int r = 0; r < 4; r++) {
                int row = arow_base + m0 + wr * 64 + i * 16 + q * 4 + r;
#pragma unroll
                for (int j = 0; j < 4; j++)
                    dexp[(size_t)row * Dd + n0 + wc * 64 + j * 16 + m] = acc[i][j][r];
            }
    }
}

// ---------------------------------------------------------------------------
// combine: out[t] += w0*dexp[slot0] + w1*dexp[slot1]  (one block per token,
// exactly one writer per element -> no atomics)
// ---------------------------------------------------------------------------
__global__ __launch_bounds__(256) void combine_kernel(
    const float* __restrict__ dexp, const int* __restrict__ slot,
    const float* __restrict__ swt, float* __restrict__ out)
{
    const int t = blockIdx.x, tid = threadIdx.x;
    const int s0 = slot[t * 2], s1 = slot[t * 2 + 1];
    const float w0 = swt[t * 2], w1 = swt[t * 2 + 1];
    const float4* d0 = (const float4*)(dexp + (size_t)s0 * Dd);
    const float4* d1 = (const float4*)(dexp + (size_t)s1 * Dd);
    float4* o = (float4*)(out + (size_t)t * Dd);
#pragma unroll
    for (int it = 0; it < 2; ++it) {
        int i = tid + it * 256;
        float4 a = o[i], b0 = d0[i], b1 = d1[i];
        a.x += w0 * b0.x + w1 * b1.x;
        a.y += w0 * b0.y + w1 * b1.y;
        a.z += w0 * b0.z + w1 * b1.z;
        a.w += w0 * b0.w + w1 * b1.w;
        o[i] = a;
    }
}

// ---------------------------------------------------------------------------
// launch
// ---------------------------------------------------------------------------
extern "C" void kernel_launch(void* const* d_in, const int* in_sizes, int n_in,
                              void* d_out, int out_size, void* d_ws, size_t ws_size,
                              hipStream_t stream) {
    const float* x        = (const float*)d_in[0];
    const float* gate_w   = (const float*)d_in[1];
    const float* w_gate   = (const float*)d_in[2];
    const float* w_up     = (const float*)d_in[3];
    const float* w_down   = (const float*)d_in[4];
    const float* shgate_w = (const float*)d_in[5];
    const float* shw_gate = (const float*)d_in[6];
    const float* shw_up   = (const float*)d_in[7];
    const float* shw_down = (const float*)d_in[8];
    float* out = (float*)d_out;

    // ---- workspace layout (bytes, 256-aligned) ----
    char* ws = (char*)d_ws;
    size_t off = 0;
    auto alloc = [&](size_t bytes) { char* p = ws + off; off = (off + bytes + 255) & ~(size_t)255; return p; };
    int*    cnt    = (int*)   alloc(Ee * 4);
    int*    ptok   = (int*)   alloc(Ee * CAP * 4);
    int*    slot   = (int*)   alloc(T_TOK * 2 * 4);
    float*  swt    = (float*) alloc(T_TOK * 2 * 4);
    float*  sgate  = (float*) alloc(T_TOK * 4);
    __bf16* xb     = (__bf16*)alloc((size_t)T_TOK * Dd * 2);
    __bf16* wgT    = (__bf16*)alloc((size_t)Ee * Hh * Dd * 2);
    __bf16* wuT    = (__bf16*)alloc((size_t)Ee * Hh * Dd * 2);
    __bf16* wdT    = (__bf16*)alloc((size_t)Ee * Dd * Hh * 2);
    __bf16* shwgT  = (__bf16*)alloc((size_t)HSs * Dd * 2);
    __bf16* shwuT  = (__bf16*)alloc((size_t)HSs * Dd * 2);
    __bf16* shwdT  = (__bf16*)alloc((size_t)Dd * HSs * 2);
    __bf16* hq     = (__bf16*)alloc((size_t)Ee * CAP * Hh * 2);
    __bf16* shh    = (__bf16*)alloc((size_t)T_TOK * HSs * 2);
    // dexp (E*CAP x D fp32 = 67 MB) aliases wgT+wuT (92 MB contiguous):
    // wgT/wuT are dead after gateup_all; down_all writes dexp, combine reads it,
    // and next iteration's transposes rewrite wgT before it is read again.
    float* dexp = (float*)wgT;

    dim3 b256(256), bT(32, 8);

    init_cnt<<<dim3(1), dim3(64), 0, stream>>>(cnt);
    // weight transposes: src [R][C] fp32 -> dst [C][R] bf16
    transpose_cvt<<<dim3(Hh / 32, Dd / 32, Ee), bT, 0, stream>>>(w_gate, wgT, Dd, Hh);
    transpose_cvt<<<dim3(Hh / 32, Dd / 32, Ee), bT, 0, stream>>>(w_up, wuT, Dd, Hh);
    transpose_cvt<<<dim3(Dd / 32, Hh / 32, Ee), bT, 0, stream>>>(w_down, wdT, Hh, Dd);
    transpose_cvt<<<dim3(HSs / 32, Dd / 32, 1), bT, 0, stream>>>(shw_gate, shwgT, Dd, HSs);
    transpose_cvt<<<dim3(HSs / 32, Dd / 32, 1), bT, 0, stream>>>(shw_up, shwuT, Dd, HSs);
    transpose_cvt<<<dim3(Dd / 32, HSs / 32, 1), bT, 0, stream>>>(shw_down, shwdT, HSs, Dd);

    router_kernel<<<dim3(T_TOK), b256, 0, stream>>>(x, gate_w, shgate_w,
                                                    cnt, ptok, slot, swt, sgate, xb);

    gateup_all<<<dim3(GU_SH_BLOCKS + GU_EX_BLOCKS), b256, 0, stream>>>(
        xb, wgT, wuT, shwgT, shwuT, cnt, ptok, hq, shh);

    down_all<<<dim3(DN_SH_BLOCKS + DN_EX_BLOCKS), b256, 0, stream>>>(
        shh, shwdT, hq, wdT, cnt, sgate, out, dexp);

    combine_kernel<<<dim3(T_TOK), b256, 0, stream>>>(dexp, slot, swt, out);
}

// Round 3
// 674.455 us; speedup vs baseline: 1.1331x; 1.0167x over previous
//
#include <hip/hip_runtime.h>
#include <hip/hip_bf16.h>
#include <math.h>

// Problem constants (B=2, L=1024 -> T=2048 tokens)
#define T_TOK 2048
#define Dd    2048
#define Ee    8
#define Hh    1408
#define HSs   2816
#define CAP   1024   // per-expert token capacity (mean 512, sigma ~21)

typedef __attribute__((ext_vector_type(8))) __bf16 bf16x8;
typedef __attribute__((ext_vector_type(4))) __bf16 bf16x4;
typedef __attribute__((ext_vector_type(4))) float  f32x4;

#define MFMA(a, b, c) __builtin_amdgcn_mfma_f32_16x16x32_bf16(a, b, c, 0, 0, 0)

// counted waits (T4): literal-immediate s_waitcnt, "memory" clobber keeps
// the compiler from hoisting LDS reads across the wait.
#define VMCNT4() asm volatile("s_waitcnt vmcnt(4)" ::: "memory")
#define VMCNT0() asm volatile("s_waitcnt vmcnt(0)" ::: "memory")
#define BAR()    __builtin_amdgcn_s_barrier()

// async global->LDS 16B/lane copy (lane-contiguous LDS dest required)
__device__ __forceinline__ void async_copy16(const __bf16* g, __bf16* l) {
    __builtin_amdgcn_global_load_lds(
        (const __attribute__((address_space(1))) unsigned int*)g,
        (__attribute__((address_space(3))) unsigned int*)l, 16, 0, 0);
}

// ---------------------------------------------------------------------------
// LDS anti-bank-conflict swizzle (T2, both-sides-or-neither per rule #21):
// tiles are [rows][32] bf16 = [rows][4 colblocks of 16B]. Linear row stride
// 64B makes 16-lane fragment reads 8-way bank-conflicted. We permute
// colblocks: physical cb = logical cb ^ ((row>>1)&3).
//  - staging: LDS dest stays lane-linear (tid*16B); the global SOURCE lane
//    offset is pre-swizzled: kq = ((tid&3) ^ ((tid>>3)&3)) * 8 elems.
//  - reads: fragment row = (mult-of-8) + m, so read colblock = q ^ ((m>>1)&3).
// Verified round 2: SQ_LDS_BANK_CONFLICT 15.5M -> 0.
// ---------------------------------------------------------------------------

// ---------------------------------------------------------------------------
// init: zero per-expert counters
// ---------------------------------------------------------------------------
__global__ void init_cnt(int* __restrict__ cnt) {
    if (threadIdx.x < Ee) cnt[threadIdx.x] = 0;
}

// ---------------------------------------------------------------------------
// router (fp32): logits, top-2 renorm weights, packed per-expert lists,
// per-token (slot, weight) for the combine pass, shared sigmoid gate.
// Also emits xb (bf16 cast of x) since we're already streaming x.
// ---------------------------------------------------------------------------
__global__ __launch_bounds__(256) void router_kernel(
    const float* __restrict__ x, const float* __restrict__ gate_w,
    const float* __restrict__ shgate_w,
    int* __restrict__ cnt, int* __restrict__ ptok,
    int* __restrict__ slot, float* __restrict__ swt,
    float* __restrict__ sgate, __bf16* __restrict__ xb)
{
    const int t = blockIdx.x;
    const int tid = threadIdx.x;
    const float* xt = x + (size_t)t * Dd;

    float acc[Ee];
#pragma unroll
    for (int e = 0; e < Ee; e++) acc[e] = 0.f;
    float accs = 0.f;

    for (int d = tid; d < Dd; d += 256) {
        float xv = xt[d];
        xb[(size_t)t * Dd + d] = (__bf16)xv;
#pragma unroll
        for (int e = 0; e < Ee; e++) acc[e] += xv * gate_w[e * Dd + d];
        accs += xv * shgate_w[d];
    }

    __shared__ float red[Ee + 1][256];
#pragma unroll
    for (int e = 0; e < Ee; e++) red[e][tid] = acc[e];
    red[Ee][tid] = accs;
    __syncthreads();

    for (int s = 128; s > 0; s >>= 1) {
        if (tid < s) {
#pragma unroll
            for (int e = 0; e <= Ee; e++) red[e][tid] += red[e][tid + s];
        }
        __syncthreads();
    }

    if (tid == 0) {
        float l0 = -1e30f, l1 = -1e30f;
        int i0 = 0, i1 = 0;
#pragma unroll
        for (int e = 0; e < Ee; e++) {
            float v = red[e][0];
            if (v > l0) { l1 = l0; i1 = i0; l0 = v; i0 = e; }
            else if (v > l1) { l1 = v; i1 = e; }
        }
        float w0 = 1.f / (1.f + expf(l1 - l0));  // renormalized top-2
        float w1 = 1.f - w0;

        int p0 = atomicAdd(&cnt[i0], 1);
        if (p0 < CAP) { ptok[i0 * CAP + p0] = t; slot[t * 2] = i0 * CAP + p0; swt[t * 2] = w0; }
        else          { slot[t * 2] = 0; swt[t * 2] = 0.f; }
        int p1 = atomicAdd(&cnt[i1], 1);
        if (p1 < CAP) { ptok[i1 * CAP + p1] = t; slot[t * 2 + 1] = i1 * CAP + p1; swt[t * 2 + 1] = w1; }
        else          { slot[t * 2 + 1] = 0; swt[t * 2 + 1] = 0.f; }

        sgate[t] = 1.f / (1.f + expf(-red[Ee][0]));
    }
}

// ---------------------------------------------------------------------------
// transpose_cvt: src fp32 [R][C] (batched) -> dst bf16 [C][R]
// grid (C/32, R/32, batch), block (32, 8). 8B bf16x4 stores.
// ---------------------------------------------------------------------------
__global__ __launch_bounds__(256) void transpose_cvt(
    const float* __restrict__ src, __bf16* __restrict__ dst, int R, int C)
{
    const size_t bstride = (size_t)R * C;
    src += blockIdx.z * bstride;
    dst += blockIdx.z * bstride;
    __shared__ float tile[32][33];
    const int tx = threadIdx.x, ty = threadIdx.y;
    const int c0 = blockIdx.x * 32, r0 = blockIdx.y * 32;
#pragma unroll
    for (int j = 0; j < 4; j++)
        tile[ty + 8 * j][tx] = src[(size_t)(r0 + ty + 8 * j) * C + c0 + tx];
    __syncthreads();
    const int tid = ty * 32 + tx;
    const int cc = tid >> 3, r4 = (tid & 7) * 4;
    bf16x4 o = { (__bf16)tile[r4 + 0][cc], (__bf16)tile[r4 + 1][cc],
                 (__bf16)tile[r4 + 2][cc], (__bf16)tile[r4 + 3][cc] };
    *(bf16x4*)(dst + (size_t)(c0 + cc) * R + r0 + r4) = o;
}

// ---------------------------------------------------------------------------
// gateup_all: merged expert + shared gate/up GEMM.
// 3-buffer depth-2 pipeline, counted vmcnt(4) + raw barrier (T3+T4):
// never drains vmcnt to 0 in the main loop; tile t+1's loads get ~2
// iterations of latency cover. One barrier per K-step.
// Block = 128 rows x 64 h (gate AND up).
// ---------------------------------------------------------------------------
#define GU_SH_BLOCKS ((T_TOK / 128) * (HSs / 64))   // 16*44 = 704
#define GU_EX_BLOCKS (Ee * 8 * (Hh / 64))           // 64*22 = 1408

__global__ __launch_bounds__(256, 3) void gateup_all(
    const __bf16* __restrict__ xb,
    const __bf16* __restrict__ wgT, const __bf16* __restrict__ wuT,   // [E][H][D]
    const __bf16* __restrict__ swgT, const __bf16* __restrict__ swuT, // [HS][D]
    const int* __restrict__ cnt, const int* __restrict__ ptok,
    __bf16* __restrict__ hq, __bf16* __restrict__ shh)
{
    const int tid = threadIdx.x, lane = tid & 63, wave = tid >> 6;
    __shared__ __align__(16) __bf16 As[3 * 128 * 32];
    __shared__ __align__(16) __bf16 Bg[3 * 64 * 32];
    __shared__ __align__(16) __bf16 Bu[3 * 64 * 32];
    __shared__ int tok_s[128];

    const int bid = blockIdx.x;
    // swizzled source k-offset for staging (see swizzle comment above)
    const int kq = (((tid & 3) ^ ((tid >> 3) & 3)) * 8);
    const __bf16 *wg, *wu, *ga1, *ga2;
    __bf16* outp;
    int ostride, m0, h0;

    if (bid < GU_SH_BLOCKS) {
        // shared expert: dense rows
        int ht = bid % 44, mt = bid / 44;   // ht in low bits: weight-panel XCD locality
        m0 = mt * 128; h0 = ht * 64;
        wg = swgT; wu = swuT;
        outp = shh; ostride = HSs;
        ga1 = xb + (size_t)(m0 + (tid >> 2)) * Dd + kq;
        ga2 = xb + (size_t)(m0 + 64 + (tid >> 2)) * Dd + kq;
    } else {
        int b2 = bid - GU_SH_BLOCKS;
        int em = b2 & 63, ht = b2 >> 6;
        int e = em & 7, mt = em >> 3;       // e in low 3 bits -> expert pinned to XCD
        int n = cnt[e]; if (n > CAP) n = CAP;
        m0 = mt * 128;
        if (m0 >= n) return;
        h0 = ht * 64;
        wg = wgT + (size_t)e * Hh * Dd; wu = wuT + (size_t)e * Hh * Dd;
        outp = hq + (size_t)e * CAP * Hh; ostride = Hh;
        if (tid < 128) {
            int i = m0 + tid; int ic = i < n ? i : n - 1;
            tok_s[tid] = ptok[e * CAP + ic];
        }
        __syncthreads();
        ga1 = xb + (size_t)tok_s[tid >> 2] * Dd + kq;
        ga2 = xb + (size_t)tok_s[64 + (tid >> 2)] * Dd + kq;
    }
    const __bf16* gbg = wg + (size_t)(h0 + (tid >> 2)) * Dd + kq;
    const __bf16* gbu = wu + (size_t)(h0 + (tid >> 2)) * Dd + kq;

    f32x4 accg[2][4] = {}, accu[2][4] = {};
    const int q = lane >> 4, m = lane & 15;
    // swizzled read colblock: q ^ ((m>>1)&3), in elements
    const int cbr = (q ^ ((m >> 1) & 3)) * 8;

#define GU_STAGE(bb, k0) do {                                  \
    __bf16* As_ = As + (bb) * (128 * 32);                      \
    __bf16* Bg_ = Bg + (bb) * (64 * 32);                       \
    __bf16* Bu_ = Bu + (bb) * (64 * 32);                       \
    async_copy16(ga1 + (k0), As_ + tid * 8);                   \
    async_copy16(ga2 + (k0), As_ + (tid + 256) * 8);           \
    async_copy16(gbg + (k0), Bg_ + tid * 8);                   \
    async_copy16(gbu + (k0), Bu_ + tid * 8); } while (0)

    const int nt = Dd / 32;
    GU_STAGE(0, 0);
    GU_STAGE(1, 32);
    VMCNT4();                       // own tile-0 loads done (tile-1's 4 in flight)
    BAR();                          // all waves' tile-0 staged
    int cur = 0;
    for (int t = 0; t < nt; ++t) {
        int s2 = cur + 2; if (s2 >= 3) s2 -= 3;
        if (t + 2 < nt) GU_STAGE(s2, (t + 2) * 32);  // buf read at t-1: safe
        const __bf16* Asc = As + cur * (128 * 32);
        const __bf16* Bgc = Bg + cur * (64 * 32);
        const __bf16* Buc = Bu + cur * (64 * 32);
        bf16x8 af[2], bgf[4], buf_[4];
        af[0] = *(const bf16x8*)(Asc + (wave * 32 + m) * 32 + cbr);
        af[1] = *(const bf16x8*)(Asc + (wave * 32 + 16 + m) * 32 + cbr);
#pragma unroll
        for (int j = 0; j < 4; j++) {
            bgf[j]  = *(const bf16x8*)(Bgc + (j * 16 + m) * 32 + cbr);
            buf_[j] = *(const bf16x8*)(Buc + (j * 16 + m) * 32 + cbr);
        }
#pragma unroll
        for (int i = 0; i < 2; i++)
#pragma unroll
            for (int j = 0; j < 4; j++) {
                accg[i][j] = MFMA(af[i], bgf[j], accg[i][j]);
                accu[i][j] = MFMA(af[i], buf_[j], accu[i][j]);
            }
        // wait tile t+1 only (4 newest stay in flight); drain only at tail
        if (t + 2 < nt)      VMCNT4();
        else if (t + 1 < nt) VMCNT0();
        BAR();
        cur = cur + 1 == 3 ? 0 : cur + 1;
    }
#undef GU_STAGE

#pragma unroll
    for (int i = 0; i < 2; i++)
#pragma unroll
        for (int r = 0; r < 4; r++) {
            int row = m0 + wave * 32 + i * 16 + q * 4 + r;
#pragma unroll
            for (int j = 0; j < 4; j++) {
                int h = h0 + j * 16 + m;
                float g = accg[i][j][r], u = accu[i][j][r];
                float s = g / (1.f + __expf(-g));
                outp[(size_t)row * ostride + h] = (__bf16)(s * u);
            }
        }
}

// ---------------------------------------------------------------------------
// down_all: merged shared + expert down-proj, 128x128 tiles, same 3-buffer
// counted-vmcnt pipeline, swizzled LDS.
// Shared: out[t][d] = sgate[t] * (shh @ shwdT)   (plain store, full coverage)
// Expert: dexp[e*CAP+row][d] = hq_row @ wdT[e]   (packed rows, NO atomics)
// ---------------------------------------------------------------------------
#define DN_SH_BLOCKS ((T_TOK / 128) * (Dd / 128))   // 16*16 = 256
#define DN_EX_BLOCKS (Ee * 8 * (Dd / 128))          // 64*16 = 1024

__global__ __launch_bounds__(256, 3) void down_all(
    const __bf16* __restrict__ shh, const __bf16* __restrict__ shwdT,
    const __bf16* __restrict__ hq, const __bf16* __restrict__ wdT,
    const int* __restrict__ cnt, const float* __restrict__ sgate,
    float* __restrict__ out, float* __restrict__ dexp)
{
    const int tid = threadIdx.x, lane = tid & 63, wave = tid >> 6;
    const int wr = wave >> 1, wc = wave & 1;
    __shared__ __align__(16) __bf16 As[3 * 128 * 32];
    __shared__ __align__(16) __bf16 Bs[3 * 128 * 32];

    const int bid = blockIdx.x;
    const __bf16 *A, *BT;
    int m0, n0, K, shared_path, arow_base = 0;

    if (bid < DN_SH_BLOCKS) {
        int nt = bid & 15, mt = bid >> 4;   // nt in low bits: B-panel XCD locality
        m0 = mt * 128; n0 = nt * 128; K = HSs;
        A = shh; BT = shwdT; shared_path = 1;
    } else {
        int b2 = bid - DN_SH_BLOCKS;
        int em = b2 & 63, nt = b2 >> 6;
        int e = em & 7, mt = em >> 3;
        int n = cnt[e]; if (n > CAP) n = CAP;
        m0 = mt * 128;
        if (m0 >= n) return;
        n0 = nt * 128; K = Hh;
        A = hq + (size_t)e * CAP * Hh;       // packed rows: contiguous, no gather
        BT = wdT + (size_t)e * Dd * Hh;
        arow_base = e * CAP;
        shared_path = 0;
    }

    const int kq = (((tid & 3) ^ ((tid >> 3) & 3)) * 8);
    const __bf16* ga1 = A + (size_t)(m0 + (tid >> 2)) * K + kq;
    const __bf16* ga2 = A + (size_t)(m0 + 64 + (tid >> 2)) * K + kq;
    const __bf16* gb1 = BT + (size_t)(n0 + (tid >> 2)) * K + kq;
    const __bf16* gb2 = BT + (size_t)(n0 + 64 + (tid >> 2)) * K + kq;

    f32x4 acc[4][4] = {};
    const int q = lane >> 4, m = lane & 15;
    const int cbr = (q ^ ((m >> 1) & 3)) * 8;

#define DN_STAGE(bb, k0) do {                                  \
    __bf16* As_ = As + (bb) * (128 * 32);                      \
    __bf16* Bs_ = Bs + (bb) * (128 * 32);                      \
    async_copy16(ga1 + (k0), As_ + tid * 8);                   \
    async_copy16(ga2 + (k0), As_ + (tid + 256) * 8);           \
    async_copy16(gb1 + (k0), Bs_ + tid * 8);                   \
    async_copy16(gb2 + (k0), Bs_ + (tid + 256) * 8); } while (0)

    const int ntk = K / 32;
    DN_STAGE(0, 0);
    DN_STAGE(1, 32);
    VMCNT4();
    BAR();
    int cur = 0;
    for (int t = 0; t < ntk; ++t) {
        int s2 = cur + 2; if (s2 >= 3) s2 -= 3;
        if (t + 2 < ntk) DN_STAGE(s2, (t + 2) * 32);
        const __bf16* Asc = As + cur * (128 * 32);
        const __bf16* Bsc = Bs + cur * (128 * 32);
        bf16x8 af[4], bf[4];
#pragma unroll
        for (int i = 0; i < 4; i++) {
            af[i] = *(const bf16x8*)(Asc + (wr * 64 + i * 16 + m) * 32 + cbr);
            bf[i] = *(const bf16x8*)(Bsc + (wc * 64 + i * 16 + m) * 32 + cbr);
        }
#pragma unroll
        for (int i = 0; i < 4; i++)
#pragma unroll
            for (int j = 0; j < 4; j++)
                acc[i][j] = MFMA(af[i], bf[j], acc[i][j]);
        if (t + 2 < ntk)      VMCNT4();
        else if (t + 1 < ntk) VMCNT0();
        BAR();
        cur = cur + 1 == 3 ? 0 : cur + 1;
    }
#undef DN_STAGE

    if (shared_path) {
#pragma unroll
        for (int i = 0; i < 4; i++)
#pragma unroll
            for (int r = 0; r < 4; r++) {
                int trow = m0 + wr * 64 + i * 16 + q * 4 + r;
                float sg = sgate[trow];
#pragma unroll
                for (int j = 0; j < 4; j++)
                    out[(size_t)trow * Dd + n0 + wc * 64 + j * 16 + m] = sg * acc[i][j][r];
            }
    } else {
#pragma unroll
        for (int i = 0; i < 4; i++)
#pragma unroll
            for (int r = 0; r < 4; r++) {
                int row = arow_base + m0 + wr * 64 + i * 16 + q * 4 + r;
#pragma unroll
                for (int j = 0; j < 4; j++)
                    dexp[(size_t)row * Dd + n0 + wc * 64 + j * 16 + m] = acc[i][j][r];
            }
    }
}

// ---------------------------------------------------------------------------
// combine: out[t] += w0*dexp[slot0] + w1*dexp[slot1]  (one block per token,
// exactly one writer per element -> no atomics)
// ---------------------------------------------------------------------------
__global__ __launch_bounds__(256) void combine_kernel(
    const float* __restrict__ dexp, const int* __restrict__ slot,
    const float* __restrict__ swt, float* __restrict__ out)
{
    const int t = blockIdx.x, tid = threadIdx.x;
    const int s0 = slot[t * 2], s1 = slot[t * 2 + 1];
    const float w0 = swt[t * 2], w1 = swt[t * 2 + 1];
    const float4* d0 = (const float4*)(dexp + (size_t)s0 * Dd);
    const float4* d1 = (const float4*)(dexp + (size_t)s1 * Dd);
    float4* o = (float4*)(out + (size_t)t * Dd);
#pragma unroll
    for (int it = 0; it < 2; ++it) {
        int i = tid + it * 256;
        float4 a = o[i], b0 = d0[i], b1 = d1[i];
        a.x += w0 * b0.x + w1 * b1.x;
        a.y += w0 * b0.y + w1 * b1.y;
        a.z += w0 * b0.z + w1 * b1.z;
        a.w += w0 * b0.w + w1 * b1.w;
        o[i] = a;
    }
}

// ---------------------------------------------------------------------------
// launch
// ---------------------------------------------------------------------------
extern "C" void kernel_launch(void* const* d_in, const int* in_sizes, int n_in,
                              void* d_out, int out_size, void* d_ws, size_t ws_size,
                              hipStream_t stream) {
    const float* x        = (const float*)d_in[0];
    const float* gate_w   = (const float*)d_in[1];
    const float* w_gate   = (const float*)d_in[2];
    const float* w_up     = (const float*)d_in[3];
    const float* w_down   = (const float*)d_in[4];
    const float* shgate_w = (const float*)d_in[5];
    const float* shw_gate = (const float*)d_in[6];
    const float* shw_up   = (const float*)d_in[7];
    const float* shw_down = (const float*)d_in[8];
    float* out = (float*)d_out;

    // ---- workspace layout (bytes, 256-aligned) ----
    char* ws = (char*)d_ws;
    size_t off = 0;
    auto alloc = [&](size_t bytes) { char* p = ws + off; off = (off + bytes + 255) & ~(size_t)255; return p; };
    int*    cnt    = (int*)   alloc(Ee * 4);
    int*    ptok   = (int*)   alloc(Ee * CAP * 4);
    int*    slot   = (int*)   alloc(T_TOK * 2 * 4);
    float*  swt    = (float*) alloc(T_TOK * 2 * 4);
    float*  sgate  = (float*) alloc(T_TOK * 4);
    __bf16* xb     = (__bf16*)alloc((size_t)T_TOK * Dd * 2);
    __bf16* wgT    = (__bf16*)alloc((size_t)Ee * Hh * Dd * 2);
    __bf16* wuT    = (__bf16*)alloc((size_t)Ee * Hh * Dd * 2);
    __bf16* wdT    = (__bf16*)alloc((size_t)Ee * Dd * Hh * 2);
    __bf16* shwgT  = (__bf16*)alloc((size_t)HSs * Dd * 2);
    __bf16* shwuT  = (__bf16*)alloc((size_t)HSs * Dd * 2);
    __bf16* shwdT  = (__bf16*)alloc((size_t)Dd * HSs * 2);
    __bf16* hq     = (__bf16*)alloc((size_t)Ee * CAP * Hh * 2);
    __bf16* shh    = (__bf16*)alloc((size_t)T_TOK * HSs * 2);
    // dexp (E*CAP x D fp32 = 67 MB) aliases wgT+wuT (92 MB contiguous):
    // wgT/wuT are dead after gateup_all; down_all writes dexp, combine reads it,
    // and next iteration's transposes rewrite wgT before it is read again.
    float* dexp = (float*)wgT;

    dim3 b256(256), bT(32, 8);

    init_cnt<<<dim3(1), dim3(64), 0, stream>>>(cnt);
    // weight transposes: src [R][C] fp32 -> dst [C][R] bf16
    transpose_cvt<<<dim3(Hh / 32, Dd / 32, Ee), bT, 0, stream>>>(w_gate, wgT, Dd, Hh);
    transpose_cvt<<<dim3(Hh / 32, Dd / 32, Ee), bT, 0, stream>>>(w_up, wuT, Dd, Hh);
    transpose_cvt<<<dim3(Dd / 32, Hh / 32, Ee), bT, 0, stream>>>(w_down, wdT, Hh, Dd);
    transpose_cvt<<<dim3(HSs / 32, Dd / 32, 1), bT, 0, stream>>>(shw_gate, shwgT, Dd, HSs);
    transpose_cvt<<<dim3(HSs / 32, Dd / 32, 1), bT, 0, stream>>>(shw_up, shwuT, Dd, HSs);
    transpose_cvt<<<dim3(Dd / 32, HSs / 32, 1), bT, 0, stream>>>(shw_down, shwdT, HSs, Dd);

    router_kernel<<<dim3(T_TOK), b256, 0, stream>>>(x, gate_w, shgate_w,
                                                    cnt, ptok, slot, swt, sgate, xb);

    gateup_all<<<dim3(GU_SH_BLOCKS + GU_EX_BLOCKS), b256, 0, stream>>>(
        xb, wgT, wuT, shwgT, shwuT, cnt, ptok, hq, shh);

    down_all<<<dim3(DN_SH_BLOCKS + DN_EX_BLOCKS), b256, 0, stream>>>(
        shh, shwdT, hq, wdT, cnt, sgate, out, dexp);

    combine_kernel<<<dim3(T_TOK), b256, 0, stream>>>(dexp, slot, swt, out);
}